// Round 1
// baseline (743.455 us; speedup 1.0000x reference)
//
#include <hip/hip_runtime.h>

typedef unsigned short ushort_t;
typedef __attribute__((ext_vector_type(8))) short short8;
typedef __attribute__((ext_vector_type(4))) float floatx4;

#define T_TOK 8192
#define HDIM 1024
#define FDIM 2048
#define NEXP 8
#define TK_SLOTS (T_TOK * 2)
#define SORT_THREADS 1024
#define PER_THREAD (TK_SLOTS / SORT_THREADS)   // 16

__device__ __forceinline__ float b2f(unsigned short u) {
    union { unsigned int i; float f; } x; x.i = ((unsigned int)u) << 16; return x.f;
}
__device__ __forceinline__ unsigned short f2b(float f) {  // RNE bf16
    unsigned int u = __float_as_uint(f);
    u += 0x7FFF + ((u >> 16) & 1);
    return (unsigned short)(u >> 16);
}
__device__ __forceinline__ void gload16(const void* g, void* l) {
    // async global->LDS, 16B/lane; LDS dest = wave-uniform base + lane*16
    __builtin_amdgcn_global_load_lds((const __attribute__((address_space(1))) void*)g,
                                     (__attribute__((address_space(3))) void*)l,
                                     16, 0, 0);
}
__device__ __forceinline__ void atomAddF(float* p, float v) {
    // exactly-2 contributions per element onto zeroed buffer: order-invariant
    __hip_atomic_fetch_add(p, v, __ATOMIC_RELAXED, __HIP_MEMORY_SCOPE_AGENT);
}

// ---------------- f32 -> bf16 conversion (8 elems/thread) ----------------
__global__ __launch_bounds__(256) void cvt_kernel(
    const float* __restrict__ src, ushort_t* __restrict__ dst, int n8)
{
    int i = blockIdx.x * 256 + threadIdx.x;
    if (i >= n8) return;
    const float4* s4 = (const float4*)src;
    float4 a = s4[2 * i], b = s4[2 * i + 1];
    short8 o;
    o[0] = (short)f2b(a.x); o[1] = (short)f2b(a.y);
    o[2] = (short)f2b(a.z); o[3] = (short)f2b(a.w);
    o[4] = (short)f2b(b.x); o[5] = (short)f2b(b.y);
    o[6] = (short)f2b(b.z); o[7] = (short)f2b(b.w);
    *(short8*)&dst[(size_t)i * 8] = o;
}

// ---------------- router: f32 logits, softmax, top-2 (NO atomics) ----------------
__global__ __launch_bounds__(256) void router_kernel(
    const float* __restrict__ X, const float* __restrict__ GW,
    float* __restrict__ logits_out, int* __restrict__ tk_e,
    float* __restrict__ tk_w)
{
    __shared__ __align__(16) float gw[NEXP * HDIM];   // 32 KB
    const int tid = threadIdx.x;
#pragma unroll
    for (int c = 0; c < 8; ++c) {
        int idx = (c * 256 + tid) * 4;
        *(float4*)&gw[idx] = *(const float4*)&GW[idx];
    }
    __syncthreads();
    const int w = tid >> 6, l = tid & 63;
    const int t = blockIdx.x * 4 + w;
    float acc[NEXP];
#pragma unroll
    for (int e = 0; e < NEXP; ++e) acc[e] = 0.f;
#pragma unroll
    for (int it = 0; it < 4; ++it) {
        const int colb = it * 256 + l * 4;
        float4 xv = *(const float4*)&X[(size_t)t * HDIM + colb];
#pragma unroll
        for (int e = 0; e < NEXP; ++e) {
            float4 gv = *(const float4*)&gw[e * HDIM + colb];
            acc[e] += xv.x * gv.x + xv.y * gv.y + xv.z * gv.z + xv.w * gv.w;
        }
    }
#pragma unroll
    for (int off = 32; off >= 1; off >>= 1)
#pragma unroll
        for (int e = 0; e < NEXP; ++e) acc[e] += __shfl_xor(acc[e], off, 64);

    if (l == 0) {
        float mx = acc[0];
#pragma unroll
        for (int e = 1; e < NEXP; ++e) mx = fmaxf(mx, acc[e]);
        float p[NEXP];
#pragma unroll
        for (int e = 0; e < NEXP; ++e) p[e] = __expf(acc[e] - mx);
        int e0 = 0;
#pragma unroll
        for (int e = 1; e < NEXP; ++e) if (p[e] > p[e0]) e0 = e;  // strict >: lower idx wins ties
        int e1 = (e0 == 0) ? 1 : 0;
#pragma unroll
        for (int e = 0; e < NEXP; ++e) if (e != e0 && p[e] > p[e1]) e1 = e;
        float den = p[e0] + p[e1];
        tk_e[t * 2] = e0; tk_e[t * 2 + 1] = e1;
        tk_w[t * 2] = p[e0] / den; tk_w[t * 2 + 1] = p[e1] / den;
#pragma unroll
        for (int e = 0; e < NEXP; ++e) logits_out[(size_t)t * NEXP + e] = acc[e];
    }
}

// ---------------- single-block deterministic histogram+scan+scatter ----------------
__global__ __launch_bounds__(SORT_THREADS) void sort_kernel(
    const int* __restrict__ tk_e, const float* __restrict__ tk_w,
    int* __restrict__ counts, int* __restrict__ offsets,
    int* __restrict__ token_list, float* __restrict__ weight_list)
{
    __shared__ int hist[NEXP][SORT_THREADS];   // 32 KB
    __shared__ int offs[NEXP];
    const int thr = threadIdx.x;
    const int base = thr * PER_THREAD;

    int ev[PER_THREAD];
    int cnt[NEXP];
#pragma unroll
    for (int e = 0; e < NEXP; ++e) cnt[e] = 0;
#pragma unroll
    for (int i = 0; i < PER_THREAD; ++i) {
        ev[i] = tk_e[base + i];
#pragma unroll
        for (int e = 0; e < NEXP; ++e) cnt[e] += (ev[i] == e);
    }
#pragma unroll
    for (int e = 0; e < NEXP; ++e) hist[e][thr] = cnt[e];
    __syncthreads();

    // Hillis-Steele inclusive scan over threads, all 8 experts in parallel
    for (int off = 1; off < SORT_THREADS; off <<= 1) {
        int v[NEXP];
#pragma unroll
        for (int e = 0; e < NEXP; ++e) v[e] = (thr >= off) ? hist[e][thr - off] : 0;
        __syncthreads();
#pragma unroll
        for (int e = 0; e < NEXP; ++e) hist[e][thr] += v[e];
        __syncthreads();
    }

    if (thr == 0) {
        int s = 0;
#pragma unroll
        for (int e = 0; e < NEXP; ++e) {
            int c = hist[e][SORT_THREADS - 1];
            offs[e] = s; offsets[e] = s; counts[e] = c; s += c;
        }
    }
    __syncthreads();

    int run[NEXP];
#pragma unroll
    for (int e = 0; e < NEXP; ++e) run[e] = offs[e] + hist[e][thr] - cnt[e];  // exclusive base

#pragma unroll
    for (int i = 0; i < PER_THREAD; ++i) {
        int e = ev[i];
        int slot = 0;
#pragma unroll
        for (int ee = 0; ee < NEXP; ++ee) if (e == ee) slot = run[ee]++;
        token_list[slot] = (base + i) >> 1;
        weight_list[slot] = tk_w[base + i];
    }
}

// ---------------- fused GEMM1+GEMM3: G = silu(X@w1^T) * (X@w3^T), bf16 ----------------
// 128x128 tile, BK=32, 4 waves at 64x64. A staged once, 32 MFMA per barrier-pair.
__global__ __launch_bounds__(256) void moe_gemm13(
    const ushort_t* __restrict__ A, const ushort_t* __restrict__ W1b,
    const ushort_t* __restrict__ W3b,
    const int* __restrict__ counts, const int* __restrict__ offsets,
    const int* __restrict__ token_list, ushort_t* __restrict__ G)
{
    const int e = blockIdx.z;
    const int ne = counts[e];
    const int m0 = blockIdx.y * 128;
    if (m0 >= ne) return;
    const int n0 = blockIdx.x * 128;
    const int aoff = offsets[e];
    const ushort_t* B1w = W1b + (size_t)e * FDIM * HDIM;
    const ushort_t* B3w = W3b + (size_t)e * FDIM * HDIM;

    __shared__ __align__(16) ushort_t As[128 * 32];
    __shared__ __align__(16) ushort_t B1s[128 * 32];
    __shared__ __align__(16) ushort_t B3s[128 * 32];

    const int tid = threadIdx.x;
    const int l = tid & 63;
    const int wv = tid >> 6;
    const int wm = wv >> 1, wn = wv & 1;
    const int quad = l >> 4, tl = l & 15;

    floatx4 acc1[4][4], acc3[4][4];
#pragma unroll
    for (int i = 0; i < 4; ++i)
#pragma unroll
        for (int j = 0; j < 4; ++j)
#pragma unroll
            for (int r = 0; r < 4; ++r) { acc1[i][j][r] = 0.f; acc3[i][j][r] = 0.f; }

    // staging assignments: 512 16B-chunks per tile, chunkid = c*256 + tid
    const ushort_t* agp[2];
    const ushort_t* b1gp[2];
    const ushort_t* b3gp[2];
    ushort_t* alds[2];
    ushort_t* b1lds[2];
    ushort_t* b3lds[2];
#pragma unroll
    for (int c = 0; c < 2; ++c) {
        int chunk = c * 256 + tid;
        int row = chunk >> 2, cc = chunk & 3;
        int rowc = m0 + row; if (rowc >= ne) rowc = ne - 1;   // clamp tail rows
        size_t arow = (size_t)token_list[aoff + rowc];
        agp[c]  = A   + arow * HDIM + cc * 8;
        b1gp[c] = B1w + (size_t)(n0 + row) * HDIM + cc * 8;
        b3gp[c] = B3w + (size_t)(n0 + row) * HDIM + cc * 8;
        int base = (c * 256 + (tid & ~63)) * 8;               // wave-uniform LDS base (elems)
        alds[c]  = &As[base];
        b1lds[c] = &B1s[base];
        b3lds[c] = &B3s[base];
    }

    for (int k0 = 0; k0 < HDIM; k0 += 32) {
        gload16(agp[0]  + k0, alds[0]);
        gload16(agp[1]  + k0, alds[1]);
        gload16(b1gp[0] + k0, b1lds[0]);
        gload16(b1gp[1] + k0, b1lds[1]);
        gload16(b3gp[0] + k0, b3lds[0]);
        gload16(b3gp[1] + k0, b3lds[1]);
        __syncthreads();   // drains vmcnt: LDS tiles complete
        short8 a[4], b1[4], b3[4];
#pragma unroll
        for (int i = 0; i < 4; ++i)
            a[i] = *(const short8*)&As[(wm * 64 + i * 16 + tl) * 32 + quad * 8];
#pragma unroll
        for (int j = 0; j < 4; ++j) {
            b1[j] = *(const short8*)&B1s[(wn * 64 + j * 16 + tl) * 32 + quad * 8];
            b3[j] = *(const short8*)&B3s[(wn * 64 + j * 16 + tl) * 32 + quad * 8];
        }
#pragma unroll
        for (int i = 0; i < 4; ++i)
#pragma unroll
            for (int j = 0; j < 4; ++j) {
                acc1[i][j] = __builtin_amdgcn_mfma_f32_16x16x32_bf16(a[i], b1[j], acc1[i][j], 0, 0, 0);
                acc3[i][j] = __builtin_amdgcn_mfma_f32_16x16x32_bf16(a[i], b3[j], acc3[i][j], 0, 0, 0);
            }
        __syncthreads();   // all reads done before next stage overwrites
    }

    // epilogue: G = bf16( silu(acc1) * acc3 ); D[row = quad*4 + r][col = lane&15]
#pragma unroll
    for (int i = 0; i < 4; ++i) {
        int mrow = m0 + wm * 64 + i * 16 + quad * 4;
#pragma unroll
        for (int r = 0; r < 4; ++r) {
            int m = mrow + r;
            if (m < ne) {
#pragma unroll
                for (int j = 0; j < 4; ++j) {
                    int col = n0 + wn * 64 + j * 16 + tl;
                    size_t oidx = (size_t)(aoff + m) * FDIM + col;
                    float v1 = acc1[i][j][r];
                    float v3 = acc3[i][j][r];
                    float s = v1 / (1.f + __expf(-v1));       // silu
                    G[oidx] = f2b(s * v3);
                }
            }
        }
    }
}

// ---------------- GEMM2: OUT[tok] += w_route * (G @ w2^T), f32 atomic epilogue ----------------
// Each OUT element receives exactly 2 contributions (top-2) onto a zeroed buffer:
// two-term f32 addition is commutative => bitwise deterministic regardless of order.
__global__ __launch_bounds__(256) void moe_gemm2(
    const ushort_t* __restrict__ A /* = G */, const ushort_t* __restrict__ W2b,
    const int* __restrict__ counts, const int* __restrict__ offsets,
    const int* __restrict__ token_list, const float* __restrict__ weight_list,
    float* __restrict__ OUT)
{
    const int e = blockIdx.z;
    const int ne = counts[e];
    const int m0 = blockIdx.y * 128;
    if (m0 >= ne) return;
    const int n0 = blockIdx.x * 128;
    const int aoff = offsets[e];
    const ushort_t* Bw = W2b + (size_t)e * HDIM * FDIM;

    __shared__ __align__(16) ushort_t As[128 * 32];
    __shared__ __align__(16) ushort_t Bs[128 * 32];

    const int tid = threadIdx.x;
    const int l = tid & 63;
    const int wv = tid >> 6;
    const int wm = wv >> 1, wn = wv & 1;
    const int quad = l >> 4, tl = l & 15;

    floatx4 acc[4][4];
#pragma unroll
    for (int i = 0; i < 4; ++i)
#pragma unroll
        for (int j = 0; j < 4; ++j)
#pragma unroll
            for (int r = 0; r < 4; ++r) acc[i][j][r] = 0.f;

    const ushort_t* agp[2];
    const ushort_t* bgp[2];
    ushort_t* alds[2];
    ushort_t* blds[2];
#pragma unroll
    for (int c = 0; c < 2; ++c) {
        int chunk = c * 256 + tid;
        int row = chunk >> 2, cc = chunk & 3;
        int rowc = m0 + row; if (rowc >= ne) rowc = ne - 1;
        agp[c] = A  + (size_t)(aoff + rowc) * FDIM + cc * 8;
        bgp[c] = Bw + (size_t)(n0 + row) * FDIM + cc * 8;
        int base = (c * 256 + (tid & ~63)) * 8;
        alds[c] = &As[base];
        blds[c] = &Bs[base];
    }

    for (int k0 = 0; k0 < FDIM; k0 += 32) {
        gload16(agp[0] + k0, alds[0]);
        gload16(agp[1] + k0, alds[1]);
        gload16(bgp[0] + k0, blds[0]);
        gload16(bgp[1] + k0, blds[1]);
        __syncthreads();
        short8 a[4], b[4];
#pragma unroll
        for (int i = 0; i < 4; ++i)
            a[i] = *(const short8*)&As[(wm * 64 + i * 16 + tl) * 32 + quad * 8];
#pragma unroll
        for (int j = 0; j < 4; ++j)
            b[j] = *(const short8*)&Bs[(wn * 64 + j * 16 + tl) * 32 + quad * 8];
#pragma unroll
        for (int i = 0; i < 4; ++i)
#pragma unroll
            for (int j = 0; j < 4; ++j)
                acc[i][j] = __builtin_amdgcn_mfma_f32_16x16x32_bf16(a[i], b[j], acc[i][j], 0, 0, 0);
        __syncthreads();
    }

    // epilogue: atomic f32 scatter-add into OUT[token]
#pragma unroll
    for (int i = 0; i < 4; ++i) {
        int mrow = m0 + wm * 64 + i * 16 + quad * 4;
#pragma unroll
        for (int r = 0; r < 4; ++r) {
            int m = mrow + r;
            if (m < ne) {
                float wgt = weight_list[aoff + m];
                int tok = token_list[aoff + m];
                float* orow = OUT + (size_t)tok * HDIM;
#pragma unroll
                for (int j = 0; j < 4; ++j) {
                    int col = n0 + wn * 64 + j * 16 + tl;
                    atomAddF(&orow[col], wgt * acc[i][j][r]);
                }
            }
        }
    }
}

extern "C" void kernel_launch(void* const* d_in, const int* in_sizes, int n_in,
                              void* d_out, int out_size, void* d_ws, size_t ws_size,
                              hipStream_t stream)
{
    const float* X  = (const float*)d_in[0];   // [T, H] f32
    const float* GW = (const float*)d_in[1];   // [E, H] f32
    const float* W1 = (const float*)d_in[2];   // [E, F, H] f32
    const float* W3 = (const float*)d_in[3];   // [E, F, H] f32
    const float* W2 = (const float*)d_in[4];   // [E, H, F] f32
    float* OUT = (float*)d_out;                 // [T, H] f32 ++ [T, E] f32
    float* LOGITS = OUT + (size_t)T_TOK * HDIM;

    char* p = (char*)d_ws;
    auto take = [&](size_t b) { char* q = p; p += (b + 255) & ~(size_t)255; return q; };
    ushort_t* Xb  = (ushort_t*)take((size_t)T_TOK * HDIM * 2);          // 16 MiB bf16 X
    ushort_t* W1b = (ushort_t*)take((size_t)NEXP * FDIM * HDIM * 2);    // 32 MiB (reused for W2)
    ushort_t* W3b = (ushort_t*)take((size_t)NEXP * FDIM * HDIM * 2);    // 32 MiB
    ushort_t* C1  = (ushort_t*)take((size_t)TK_SLOTS * FDIM * 2);       // 64 MiB (G)
    int*   counts      = (int*)take(NEXP * 4);
    int*   offsets     = (int*)take(NEXP * 4);
    int*   tk_e        = (int*)take(TK_SLOTS * 4);
    float* tk_w        = (float*)take(TK_SLOTS * 4);
    int*   token_list  = (int*)take(TK_SLOTS * 4);
    float* weight_list = (float*)take(TK_SLOTS * 4);

    // zero the accumulation target (graph-capture-legal)
    hipMemsetAsync(OUT, 0, (size_t)T_TOK * HDIM * sizeof(float), stream);

    router_kernel<<<T_TOK / 4, 256, 0, stream>>>(X, GW, LOGITS, tk_e, tk_w);
    sort_kernel<<<1, SORT_THREADS, 0, stream>>>(tk_e, tk_w, counts, offsets,
                                                token_list, weight_list);
    cvt_kernel<<<(T_TOK * HDIM / 8) / 256, 256, 0, stream>>>(X, Xb, T_TOK * HDIM / 8);
    cvt_kernel<<<(NEXP * FDIM * HDIM / 8) / 256, 256, 0, stream>>>(W1, W1b, NEXP * FDIM * HDIM / 8);
    cvt_kernel<<<(NEXP * FDIM * HDIM / 8) / 256, 256, 0, stream>>>(W3, W3b, NEXP * FDIM * HDIM / 8);

    moe_gemm13<<<dim3(FDIM / 128, T_TOK / 128, NEXP), 256, 0, stream>>>(
        Xb, W1b, W3b, counts, offsets, token_list, C1);

    cvt_kernel<<<(NEXP * HDIM * FDIM / 8) / 256, 256, 0, stream>>>(W2, W1b, NEXP * HDIM * FDIM / 8);
    moe_gemm2<<<dim3(HDIM / 128, T_TOK / 128, NEXP), 256, 0, stream>>>(
        C1, W1b, counts, offsets, token_list, weight_list, OUT);
}

// Round 2
// 575.501 us; speedup vs baseline: 1.2918x; 1.2918x over previous
//
#include <hip/hip_runtime.h>

typedef unsigned short ushort_t;
typedef __attribute__((ext_vector_type(8))) short short8;
typedef __attribute__((ext_vector_type(4))) short short4v;
typedef __attribute__((ext_vector_type(4))) float floatx4;

#define T_TOK 8192
#define HDIM 1024
#define FDIM 2048
#define NEXP 8
#define TK_SLOTS (T_TOK * 2)
#define SORT_THREADS 1024
#define PER_THREAD (TK_SLOTS / SORT_THREADS)   // 16

__device__ __forceinline__ float b2f(unsigned short u) {
    union { unsigned int i; float f; } x; x.i = ((unsigned int)u) << 16; return x.f;
}
__device__ __forceinline__ unsigned short f2b(float f) {  // RNE bf16
    unsigned int u = __float_as_uint(f);
    u += 0x7FFF + ((u >> 16) & 1);
    return (unsigned short)(u >> 16);
}
__device__ __forceinline__ void gload16(const void* g, void* l) {
    // async global->LDS, 16B/lane; LDS dest = wave-uniform base + lane*16
    __builtin_amdgcn_global_load_lds((const __attribute__((address_space(1))) void*)g,
                                     (__attribute__((address_space(3))) void*)l,
                                     16, 0, 0);
}
__device__ __forceinline__ void atomAddF(float* p, float v) {
    // exactly-2 contributions per element onto zeroed buffer: order-invariant
    __hip_atomic_fetch_add(p, v, __ATOMIC_RELAXED, __HIP_MEMORY_SCOPE_AGENT);
}

// ---------------- f32 -> bf16 conversion (8 elems/thread) ----------------
__global__ __launch_bounds__(256) void cvt_kernel(
    const float* __restrict__ src, ushort_t* __restrict__ dst, int n8)
{
    int i = blockIdx.x * 256 + threadIdx.x;
    if (i >= n8) return;
    const float4* s4 = (const float4*)src;
    float4 a = s4[2 * i], b = s4[2 * i + 1];
    short8 o;
    o[0] = (short)f2b(a.x); o[1] = (short)f2b(a.y);
    o[2] = (short)f2b(a.z); o[3] = (short)f2b(a.w);
    o[4] = (short)f2b(b.x); o[5] = (short)f2b(b.y);
    o[6] = (short)f2b(b.z); o[7] = (short)f2b(b.w);
    *(short8*)&dst[(size_t)i * 8] = o;
}

// two-source variant: converts W1 and W3 in one dispatch (blockIdx.y selects)
__global__ __launch_bounds__(256) void wcvt_kernel(
    const float* __restrict__ s1, const float* __restrict__ s3,
    ushort_t* __restrict__ d1, ushort_t* __restrict__ d3, int n8)
{
    const float* src = blockIdx.y ? s3 : s1;
    ushort_t* dst = blockIdx.y ? d3 : d1;
    int i = blockIdx.x * 256 + threadIdx.x;
    if (i >= n8) return;
    const float4* s4 = (const float4*)src;
    float4 a = s4[2 * i], b = s4[2 * i + 1];
    short8 o;
    o[0] = (short)f2b(a.x); o[1] = (short)f2b(a.y);
    o[2] = (short)f2b(a.z); o[3] = (short)f2b(a.w);
    o[4] = (short)f2b(b.x); o[5] = (short)f2b(b.y);
    o[6] = (short)f2b(b.z); o[7] = (short)f2b(b.w);
    *(short8*)&dst[(size_t)i * 8] = o;
}

// ---------------- router: f32 logits, softmax, top-2, + X bf16 side-write ----------------
__global__ __launch_bounds__(256) void router_kernel(
    const float* __restrict__ X, const float* __restrict__ GW,
    float* __restrict__ logits_out, int* __restrict__ tk_e,
    float* __restrict__ tk_w, ushort_t* __restrict__ Xb)
{
    __shared__ __align__(16) float gw[NEXP * HDIM];   // 32 KB
    const int tid = threadIdx.x;
#pragma unroll
    for (int c = 0; c < 8; ++c) {
        int idx = (c * 256 + tid) * 4;
        *(float4*)&gw[idx] = *(const float4*)&GW[idx];
    }
    __syncthreads();
    const int w = tid >> 6, l = tid & 63;
    const int t = blockIdx.x * 4 + w;
    float acc[NEXP];
#pragma unroll
    for (int e = 0; e < NEXP; ++e) acc[e] = 0.f;
#pragma unroll
    for (int it = 0; it < 4; ++it) {
        const int colb = it * 256 + l * 4;
        float4 xv = *(const float4*)&X[(size_t)t * HDIM + colb];
        // fused f32->bf16 conversion of X (replaces a separate cvt pass)
        short4v xo;
        xo[0] = (short)f2b(xv.x); xo[1] = (short)f2b(xv.y);
        xo[2] = (short)f2b(xv.z); xo[3] = (short)f2b(xv.w);
        *(short4v*)&Xb[(size_t)t * HDIM + colb] = xo;
#pragma unroll
        for (int e = 0; e < NEXP; ++e) {
            float4 gv = *(const float4*)&gw[e * HDIM + colb];
            acc[e] += xv.x * gv.x + xv.y * gv.y + xv.z * gv.z + xv.w * gv.w;
        }
    }
#pragma unroll
    for (int off = 32; off >= 1; off >>= 1)
#pragma unroll
        for (int e = 0; e < NEXP; ++e) acc[e] += __shfl_xor(acc[e], off, 64);

    if (l == 0) {
        float mx = acc[0];
#pragma unroll
        for (int e = 1; e < NEXP; ++e) mx = fmaxf(mx, acc[e]);
        float p[NEXP];
#pragma unroll
        for (int e = 0; e < NEXP; ++e) p[e] = __expf(acc[e] - mx);
        int e0 = 0;
#pragma unroll
        for (int e = 1; e < NEXP; ++e) if (p[e] > p[e0]) e0 = e;  // strict >: lower idx wins ties
        int e1 = (e0 == 0) ? 1 : 0;
#pragma unroll
        for (int e = 0; e < NEXP; ++e) if (e != e0 && p[e] > p[e1]) e1 = e;
        float den = p[e0] + p[e1];
        tk_e[t * 2] = e0; tk_e[t * 2 + 1] = e1;
        tk_w[t * 2] = p[e0] / den; tk_w[t * 2 + 1] = p[e1] / den;
#pragma unroll
        for (int e = 0; e < NEXP; ++e) logits_out[(size_t)t * NEXP + e] = acc[e];
    }
}

// ---------------- single-block deterministic histogram+scan+scatter ----------------
__global__ __launch_bounds__(SORT_THREADS) void sort_kernel(
    const int* __restrict__ tk_e, const float* __restrict__ tk_w,
    int* __restrict__ counts, int* __restrict__ offsets,
    int* __restrict__ token_list, float* __restrict__ weight_list)
{
    __shared__ int hist[NEXP][SORT_THREADS];   // 32 KB
    __shared__ int offs[NEXP];
    const int thr = threadIdx.x;
    const int base = thr * PER_THREAD;

    int ev[PER_THREAD];
    int cnt[NEXP];
#pragma unroll
    for (int e = 0; e < NEXP; ++e) cnt[e] = 0;
#pragma unroll
    for (int i = 0; i < PER_THREAD; ++i) {
        ev[i] = tk_e[base + i];
#pragma unroll
        for (int e = 0; e < NEXP; ++e) cnt[e] += (ev[i] == e);
    }
#pragma unroll
    for (int e = 0; e < NEXP; ++e) hist[e][thr] = cnt[e];
    __syncthreads();

    // Hillis-Steele inclusive scan over threads, all 8 experts in parallel
    for (int off = 1; off < SORT_THREADS; off <<= 1) {
        int v[NEXP];
#pragma unroll
        for (int e = 0; e < NEXP; ++e) v[e] = (thr >= off) ? hist[e][thr - off] : 0;
        __syncthreads();
#pragma unroll
        for (int e = 0; e < NEXP; ++e) hist[e][thr] += v[e];
        __syncthreads();
    }

    if (thr == 0) {
        int s = 0;
#pragma unroll
        for (int e = 0; e < NEXP; ++e) {
            int c = hist[e][SORT_THREADS - 1];
            offs[e] = s; offsets[e] = s; counts[e] = c; s += c;
        }
    }
    __syncthreads();

    int run[NEXP];
#pragma unroll
    for (int e = 0; e < NEXP; ++e) run[e] = offs[e] + hist[e][thr] - cnt[e];  // exclusive base

#pragma unroll
    for (int i = 0; i < PER_THREAD; ++i) {
        int e = ev[i];
        int slot = 0;
#pragma unroll
        for (int ee = 0; ee < NEXP; ++ee) if (e == ee) slot = run[ee]++;
        token_list[slot] = (base + i) >> 1;
        weight_list[slot] = tk_w[base + i];
    }
}

// ---------------- fused GEMM1+GEMM3: G = silu(X@w1^T) * (X@w3^T), bf16 ----------------
// 128x128 tile, BK=32, 512 threads / 8 waves (2m x 4n), per-wave 64x32 per matrix.
// acc = 2 matrices x 8 frags = 64 VGPR (same budget as the proven single-GEMM kernel);
// 3 global_load_lds calls per wave per K-step vs 16 MFMA (round-0 was 4:16).
__global__ __launch_bounds__(512) void moe_gemm13(
    const ushort_t* __restrict__ A, const ushort_t* __restrict__ W1b,
    const ushort_t* __restrict__ W3b,
    const int* __restrict__ counts, const int* __restrict__ offsets,
    const int* __restrict__ token_list, ushort_t* __restrict__ G)
{
    const int e = blockIdx.z;
    const int ne = counts[e];
    const int m0 = blockIdx.y * 128;
    if (m0 >= ne) return;
    const int n0 = blockIdx.x * 128;
    const int aoff = offsets[e];
    const ushort_t* B1w = W1b + (size_t)e * FDIM * HDIM;
    const ushort_t* B3w = W3b + (size_t)e * FDIM * HDIM;

    __shared__ __align__(16) ushort_t As[128 * 32];
    __shared__ __align__(16) ushort_t B1s[128 * 32];
    __shared__ __align__(16) ushort_t B3s[128 * 32];

    const int tid = threadIdx.x;          // 0..511
    const int l = tid & 63;
    const int wv = tid >> 6;              // 0..7
    const int wm = wv >> 2, wn = wv & 3;  // 2 x 4 wave grid
    const int quad = l >> 4, tl = l & 15;

    floatx4 acc1[4][2], acc3[4][2];
#pragma unroll
    for (int i = 0; i < 4; ++i)
#pragma unroll
        for (int j = 0; j < 2; ++j)
#pragma unroll
            for (int r = 0; r < 4; ++r) { acc1[i][j][r] = 0.f; acc3[i][j][r] = 0.f; }

    // staging: 512 threads = 512 x 16B chunks per 8KB tile (one chunk each)
    const int row = tid >> 2, cc = tid & 3;
    int rowc = m0 + row; if (rowc >= ne) rowc = ne - 1;   // clamp tail rows
    const ushort_t* agp  = A   + (size_t)token_list[aoff + rowc] * HDIM + cc * 8;
    const ushort_t* b1gp = B1w + (size_t)(n0 + row) * HDIM + cc * 8;
    const ushort_t* b3gp = B3w + (size_t)(n0 + row) * HDIM + cc * 8;
    const int ldsbase = (tid & ~63) * 8;                  // wave-uniform LDS base (elems)
    ushort_t* alds  = &As[ldsbase];
    ushort_t* b1lds = &B1s[ldsbase];
    ushort_t* b3lds = &B3s[ldsbase];

    for (int k0 = 0; k0 < HDIM; k0 += 32) {
        gload16(agp  + k0, alds);
        gload16(b1gp + k0, b1lds);
        gload16(b3gp + k0, b3lds);
        __syncthreads();   // drains vmcnt: LDS tiles complete
        short8 a[4], b1[2], b3[2];
#pragma unroll
        for (int i = 0; i < 4; ++i)
            a[i] = *(const short8*)&As[(wm * 64 + i * 16 + tl) * 32 + quad * 8];
#pragma unroll
        for (int j = 0; j < 2; ++j) {
            b1[j] = *(const short8*)&B1s[(wn * 32 + j * 16 + tl) * 32 + quad * 8];
            b3[j] = *(const short8*)&B3s[(wn * 32 + j * 16 + tl) * 32 + quad * 8];
        }
#pragma unroll
        for (int i = 0; i < 4; ++i)
#pragma unroll
            for (int j = 0; j < 2; ++j) {
                acc1[i][j] = __builtin_amdgcn_mfma_f32_16x16x32_bf16(a[i], b1[j], acc1[i][j], 0, 0, 0);
                acc3[i][j] = __builtin_amdgcn_mfma_f32_16x16x32_bf16(a[i], b3[j], acc3[i][j], 0, 0, 0);
            }
        __syncthreads();   // all reads done before next stage overwrites
    }

    // epilogue: G = bf16( silu(acc1) * acc3 ); D[row = quad*4 + r][col = lane&15]
#pragma unroll
    for (int i = 0; i < 4; ++i) {
        int mrow = m0 + wm * 64 + i * 16 + quad * 4;
#pragma unroll
        for (int r = 0; r < 4; ++r) {
            int m = mrow + r;
            if (m < ne) {
#pragma unroll
                for (int j = 0; j < 2; ++j) {
                    int col = n0 + wn * 32 + j * 16 + tl;
                    size_t oidx = (size_t)(aoff + m) * FDIM + col;
                    float v1 = acc1[i][j][r];
                    float v3 = acc3[i][j][r];
                    float s = v1 / (1.f + __expf(-v1));       // silu
                    G[oidx] = f2b(s * v3);
                }
            }
        }
    }
}

// ---------------- GEMM2: OUT[tok] += w_route * (G @ w2^T), f32 atomic epilogue ----------------
// Each OUT element receives exactly 2 contributions (top-2) onto a zeroed buffer:
// two-term f32 addition is commutative => bitwise deterministic regardless of order.
__global__ __launch_bounds__(256) void moe_gemm2(
    const ushort_t* __restrict__ A /* = G */, const ushort_t* __restrict__ W2b,
    const int* __restrict__ counts, const int* __restrict__ offsets,
    const int* __restrict__ token_list, const float* __restrict__ weight_list,
    float* __restrict__ OUT)
{
    const int e = blockIdx.z;
    const int ne = counts[e];
    const int m0 = blockIdx.y * 128;
    if (m0 >= ne) return;
    const int n0 = blockIdx.x * 128;
    const int aoff = offsets[e];
    const ushort_t* Bw = W2b + (size_t)e * HDIM * FDIM;

    __shared__ __align__(16) ushort_t As[128 * 32];
    __shared__ __align__(16) ushort_t Bs[128 * 32];

    const int tid = threadIdx.x;
    const int l = tid & 63;
    const int wv = tid >> 6;
    const int wm = wv >> 1, wn = wv & 1;
    const int quad = l >> 4, tl = l & 15;

    floatx4 acc[4][4];
#pragma unroll
    for (int i = 0; i < 4; ++i)
#pragma unroll
        for (int j = 0; j < 4; ++j)
#pragma unroll
            for (int r = 0; r < 4; ++r) acc[i][j][r] = 0.f;

    const ushort_t* agp[2];
    const ushort_t* bgp[2];
    ushort_t* alds[2];
    ushort_t* blds[2];
#pragma unroll
    for (int c = 0; c < 2; ++c) {
        int chunk = c * 256 + tid;
        int row = chunk >> 2, cc = chunk & 3;
        int rowc = m0 + row; if (rowc >= ne) rowc = ne - 1;
        agp[c] = A  + (size_t)(aoff + rowc) * FDIM + cc * 8;
        bgp[c] = Bw + (size_t)(n0 + row) * FDIM + cc * 8;
        int base = (c * 256 + (tid & ~63)) * 8;
        alds[c] = &As[base];
        blds[c] = &Bs[base];
    }

    for (int k0 = 0; k0 < FDIM; k0 += 32) {
        gload16(agp[0] + k0, alds[0]);
        gload16(agp[1] + k0, alds[1]);
        gload16(bgp[0] + k0, blds[0]);
        gload16(bgp[1] + k0, blds[1]);
        __syncthreads();
        short8 a[4], b[4];
#pragma unroll
        for (int i = 0; i < 4; ++i)
            a[i] = *(const short8*)&As[(wm * 64 + i * 16 + tl) * 32 + quad * 8];
#pragma unroll
        for (int j = 0; j < 4; ++j)
            b[j] = *(const short8*)&Bs[(wn * 64 + j * 16 + tl) * 32 + quad * 8];
#pragma unroll
        for (int i = 0; i < 4; ++i)
#pragma unroll
            for (int j = 0; j < 4; ++j)
                acc[i][j] = __builtin_amdgcn_mfma_f32_16x16x32_bf16(a[i], b[j], acc[i][j], 0, 0, 0);
        __syncthreads();
    }

    // epilogue: atomic f32 scatter-add into OUT[token]
#pragma unroll
    for (int i = 0; i < 4; ++i) {
        int mrow = m0 + wm * 64 + i * 16 + quad * 4;
#pragma unroll
        for (int r = 0; r < 4; ++r) {
            int m = mrow + r;
            if (m < ne) {
                float wgt = weight_list[aoff + m];
                int tok = token_list[aoff + m];
                float* orow = OUT + (size_t)tok * HDIM;
#pragma unroll
                for (int j = 0; j < 4; ++j) {
                    int col = n0 + wn * 64 + j * 16 + tl;
                    atomAddF(&orow[col], wgt * acc[i][j][r]);
                }
            }
        }
    }
}

extern "C" void kernel_launch(void* const* d_in, const int* in_sizes, int n_in,
                              void* d_out, int out_size, void* d_ws, size_t ws_size,
                              hipStream_t stream)
{
    const float* X  = (const float*)d_in[0];   // [T, H] f32
    const float* GW = (const float*)d_in[1];   // [E, H] f32
    const float* W1 = (const float*)d_in[2];   // [E, F, H] f32
    const float* W3 = (const float*)d_in[3];   // [E, F, H] f32
    const float* W2 = (const float*)d_in[4];   // [E, H, F] f32
    float* OUT = (float*)d_out;                 // [T, H] f32 ++ [T, E] f32
    float* LOGITS = OUT + (size_t)T_TOK * HDIM;

    char* p = (char*)d_ws;
    auto take = [&](size_t b) { char* q = p; p += (b + 255) & ~(size_t)255; return q; };
    ushort_t* Xb  = (ushort_t*)take((size_t)T_TOK * HDIM * 2);          // 16 MiB bf16 X
    ushort_t* W1b = (ushort_t*)take((size_t)NEXP * FDIM * HDIM * 2);    // 32 MiB (reused for W2)
    ushort_t* W3b = (ushort_t*)take((size_t)NEXP * FDIM * HDIM * 2);    // 32 MiB
    ushort_t* C1  = (ushort_t*)take((size_t)TK_SLOTS * FDIM * 2);       // 64 MiB (G)
    int*   counts      = (int*)take(NEXP * 4);
    int*   offsets     = (int*)take(NEXP * 4);
    int*   tk_e        = (int*)take(TK_SLOTS * 4);
    float* tk_w        = (float*)take(TK_SLOTS * 4);
    int*   token_list  = (int*)take(TK_SLOTS * 4);
    float* weight_list = (float*)take(TK_SLOTS * 4);

    // zero the accumulation target (graph-capture-legal)
    hipMemsetAsync(OUT, 0, (size_t)T_TOK * HDIM * sizeof(float), stream);

    router_kernel<<<T_TOK / 4, 256, 0, stream>>>(X, GW, LOGITS, tk_e, tk_w, Xb);
    sort_kernel<<<1, SORT_THREADS, 0, stream>>>(tk_e, tk_w, counts, offsets,
                                                token_list, weight_list);
    wcvt_kernel<<<dim3((NEXP * FDIM * HDIM / 8) / 256, 2), 256, 0, stream>>>(
        W1, W3, W1b, W3b, NEXP * FDIM * HDIM / 8);

    moe_gemm13<<<dim3(FDIM / 128, T_TOK / 128, NEXP), 512, 0, stream>>>(
        Xb, W1b, W3b, counts, offsets, token_list, C1);

    cvt_kernel<<<(NEXP * HDIM * FDIM / 8) / 256, 256, 0, stream>>>(W2, W1b, NEXP * HDIM * FDIM / 8);
    moe_gemm2<<<dim3(HDIM / 128, T_TOK / 128, NEXP), 256, 0, stream>>>(
        C1, W1b, counts, offsets, token_list, weight_list, OUT);
}